// Round 10
// baseline (868.953 us; speedup 1.0000x reference)
//
#include <hip/hip_runtime.h>

#define N_NODES 50000
#define N_EDGES 1600000
#define D_FEAT 32

typedef float f4 __attribute__((ext_vector_type(4)));

// out = (1+eps) * node_feat  (residual pre-init; fuse_scatter accumulates on top)
__global__ void init_out(const float* __restrict__ node_feat,
                         const float* __restrict__ eps,
                         float* __restrict__ out) {
    int i = blockIdx.x * blockDim.x + threadIdx.x;
    const int n4 = N_NODES * D_FEAT / 4;
    float scale = 1.0f + eps[0];
    if (i < n4) {
        f4 v = ((const f4*)node_feat)[i];
        ((f4*)out)[i] = v * scale;
    }
}

// Direct fused message+aggregate: 8 lanes per edge, edge_feat read fully
// coalesced in natural order (the 204.8 MB dominant array moves at street
// HBM rate instead of 2.8 TB/s random-row rate). Aggregation via
// fire-and-forget fp32 atomics into out (6.4 MB, cache-resident).
// No metadata pipeline: no hist/scan/rank/scatter kernels at all.
__global__ void fuse_scatter(const float* __restrict__ node_feat,
                             const float* __restrict__ edge_feat,
                             const int* __restrict__ src,
                             const int* __restrict__ dst,
                             float* __restrict__ out) {
    int t = blockIdx.x * blockDim.x + threadIdx.x;
    int e = t >> 3;
    int g = t & 7;
    if (e >= N_EDGES) return;
    int s = src[e];   // 8 lanes read same value; HW coalesces to one request
    int d = dst[e];
    f4 ef = ((const f4*)edge_feat)[(size_t)e * 8 + g];   // 16B/lane, coalesced
    f4 nf = ((const f4*)node_feat)[(size_t)s * 8 + g];   // gather, L2/L3-hot
    float m0 = fmaxf(nf.x + ef.x, 0.f);
    float m1 = fmaxf(nf.y + ef.y, 0.f);
    float m2 = fmaxf(nf.z + ef.z, 0.f);
    float m3 = fmaxf(nf.w + ef.w, 0.f);
    float* op = out + (size_t)d * D_FEAT + g * 4;
    unsafeAtomicAdd(op + 0, m0);
    unsafeAtomicAdd(op + 1, m1);
    unsafeAtomicAdd(op + 2, m2);
    unsafeAtomicAdd(op + 3, m3);
}

extern "C" void kernel_launch(void* const* d_in, const int* in_sizes, int n_in,
                              void* d_out, int out_size, void* d_ws, size_t ws_size,
                              hipStream_t stream) {
    const float* node_feat = (const float*)d_in[0];
    const float* edge_feat = (const float*)d_in[1];
    const float* eps       = (const float*)d_in[2];
    const int*   src       = (const int*)d_in[3];
    const int*   dst       = (const int*)d_in[4];
    float* out = (float*)d_out;

    const int B = 256;

    int n4 = N_NODES * D_FEAT / 4;
    init_out<<<(n4 + B - 1) / B, B, 0, stream>>>(node_feat, eps, out);

    long long total = (long long)N_EDGES * 8;
    fuse_scatter<<<(int)((total + B - 1) / B), B, 0, stream>>>(
        node_feat, edge_feat, src, dst, out);
}

// Round 11
// 428.595 us; speedup vs baseline: 2.0274x; 2.0274x over previous
//
#include <hip/hip_runtime.h>

#define N_NODES 50000
#define N_EDGES 1600000
#define D_FEAT 32
#define SCAN_BLOCK 1024
#define N_SCAN_BLOCKS ((N_NODES + SCAN_BLOCK - 1) / SCAN_BLOCK)  // 49

// ws layout (int units):
//   cnt   [0, N)          per-dst edge count (histogram)
//   excl  [N, 2N)         per-block exclusive scan of cnt
//   bsum  [2N, 2N+64)
//   bsumx [2N+64, 2N+128)
//   rank  [2N+128, 2N+128+E)       rank of edge within its dst bin
//   pair  [2N+128+E, 2N+128+3E)    int2 {e, src[e]} sorted by dst (12.8 MB)
#define WS_CNT   0
#define WS_EXCL  (N_NODES)
#define WS_BSUM  (2 * N_NODES)
#define WS_BSUMX (2 * N_NODES + 64)
#define WS_RANK  (2 * N_NODES + 128)
#define WS_PAIR  (2 * N_NODES + 128 + N_EDGES)

typedef float f4 __attribute__((ext_vector_type(4)));

// -------- main path --------

// rank[e] = old count of dst[e]; cnt accumulates histogram.
// int4-vectorized: 4 edges/thread, 4 independent atomics, coalesced int4 rank store.
__global__ void hist_rank(const int* __restrict__ dst,
                          int* __restrict__ cnt,
                          int* __restrict__ rank) {
    int q = blockIdx.x * blockDim.x + threadIdx.x;
    const int NQ = N_EDGES / 4;
    if (q >= NQ) return;
    int4 d4 = ((const int4*)dst)[q];
    int4 r4;
    r4.x = atomicAdd(&cnt[d4.x], 1);
    r4.y = atomicAdd(&cnt[d4.y], 1);
    r4.z = atomicAdd(&cnt[d4.z], 1);
    r4.w = atomicAdd(&cnt[d4.w], 1);
    ((int4*)rank)[q] = r4;
}

__global__ void scan_blocks(const int* __restrict__ cnt,
                            int* __restrict__ excl,
                            int* __restrict__ bsum) {
    __shared__ int lds[SCAN_BLOCK];
    int tid = threadIdx.x;
    int i = blockIdx.x * SCAN_BLOCK + tid;
    int v = (i < N_NODES) ? cnt[i] : 0;
    int sum = v;
    lds[tid] = v;
    __syncthreads();
    for (int ofs = 1; ofs < SCAN_BLOCK; ofs <<= 1) {
        int t = (tid >= ofs) ? lds[tid - ofs] : 0;
        __syncthreads();
        sum += t;
        lds[tid] = sum;
        __syncthreads();
    }
    if (i < N_NODES) excl[i] = sum - v;
    if (tid == SCAN_BLOCK - 1) bsum[blockIdx.x] = lds[SCAN_BLOCK - 1];
}

// one wave: shuffle-based exclusive scan of the 49 block sums
__global__ void scan_bsums(const int* __restrict__ bsum, int* __restrict__ bsumx) {
    int lane = threadIdx.x;
    int orig = (lane < N_SCAN_BLOCKS) ? bsum[lane] : 0;
    int v = orig;
    for (int o = 1; o < 64; o <<= 1) {
        int t = __shfl_up(v, o);
        if (lane >= o) v += t;
    }
    if (lane < N_SCAN_BLOCKS) bsumx[lane] = v - orig;
}

// Scatter 8-byte records {e, src[e]} to dst-sorted positions (rank-based, no
// atomics in the store path -> fire-and-forget stores at full rate).
// off[d] computed inline as excl[d] + bsumx[d>>10]. 4 edges/thread, int4 reads.
__global__ void scatter_pairs(const int* __restrict__ src,
                              const int* __restrict__ dst,
                              const int* __restrict__ excl,
                              const int* __restrict__ bsumx,
                              const int* __restrict__ rank,
                              int2* __restrict__ pair) {
    int q = blockIdx.x * blockDim.x + threadIdx.x;
    const int NQ = N_EDGES / 4;
    if (q >= NQ) return;
    int4 d4 = ((const int4*)dst)[q];
    int4 s4 = ((const int4*)src)[q];
    int4 r4 = ((const int4*)rank)[q];
    int e0 = q * 4;
    pair[excl[d4.x] + bsumx[d4.x >> 10] + r4.x] = make_int2(e0,     s4.x);
    pair[excl[d4.y] + bsumx[d4.y >> 10] + r4.y] = make_int2(e0 + 1, s4.y);
    pair[excl[d4.z] + bsumx[d4.z >> 10] + r4.z] = make_int2(e0 + 2, s4.z);
    pair[excl[d4.w] + bsumx[d4.w >> 10] + r4.w] = make_int2(e0 + 3, s4.w);
}

// per (node, float4-group): walk the node's contiguous pair records, gather
// edge_feat/node_feat rows, relu-sum on the fly, add eps-scaled residual.
// 8-lane groups broadcast pair records via shfl; main loop fully unrolled.
__global__ void reduce_gather(const float* __restrict__ node_feat,
                              const float* __restrict__ edge_feat,
                              const float* __restrict__ eps,
                              const int* __restrict__ excl,
                              const int* __restrict__ bsumx,
                              const int* __restrict__ cnt,
                              const int2* __restrict__ pair,
                              float* __restrict__ out) {
    int t = blockIdx.x * blockDim.x + threadIdx.x;
    int n = t >> 3;
    int g = t & 7;
    if (n >= N_NODES) return;

    int start = excl[n] + bsumx[n >> 10];
    int c = cnt[n];
    int gbase = (threadIdx.x & 63) & ~7;  // base lane of this 8-lane group

    const f4* efp = (const f4*)edge_feat;
    const f4* nfp = (const f4*)node_feat;

    f4 acc = (f4)(0.f);
    int i0 = 0;
    for (; i0 + 8 <= c; i0 += 8) {
        int2 p = pair[start + i0 + g];  // 8 lanes x 8B = 64B coalesced
#pragma unroll
        for (int j = 0; j < 8; ++j) {
            int e = __shfl(p.x, gbase + j);
            int s = __shfl(p.y, gbase + j);
            f4 ef = __builtin_nontemporal_load(&efp[(size_t)e * 8 + g]);
            f4 nf = nfp[(size_t)s * 8 + g];
            acc.x += fmaxf(nf.x + ef.x, 0.f);
            acc.y += fmaxf(nf.y + ef.y, 0.f);
            acc.z += fmaxf(nf.z + ef.z, 0.f);
            acc.w += fmaxf(nf.w + ef.w, 0.f);
        }
    }
    int rem = c - i0;
    if (rem > 0) {
        int2 p = (g < rem) ? pair[start + i0 + g] : make_int2(0, 0);
        for (int j = 0; j < rem; ++j) {
            int e = __shfl(p.x, gbase + j);
            int s = __shfl(p.y, gbase + j);
            f4 ef = __builtin_nontemporal_load(&efp[(size_t)e * 8 + g]);
            f4 nf = nfp[(size_t)s * 8 + g];
            acc.x += fmaxf(nf.x + ef.x, 0.f);
            acc.y += fmaxf(nf.y + ef.y, 0.f);
            acc.z += fmaxf(nf.z + ef.z, 0.f);
            acc.w += fmaxf(nf.w + ef.w, 0.f);
        }
    }

    float scale = 1.0f + eps[0];
    f4 h = nfp[(size_t)n * 8 + g];
    f4 o;
    o.x = scale * h.x + acc.x;
    o.y = scale * h.y + acc.y;
    o.z = scale * h.z + acc.z;
    o.w = scale * h.w + acc.w;
    ((f4*)out)[(size_t)n * 8 + g] = o;
}

// -------- fallback path (tiny ws): direct atomics --------

__global__ void fb_init_out(const float* __restrict__ node_feat,
                            const float* __restrict__ eps,
                            float* __restrict__ out) {
    int i = blockIdx.x * blockDim.x + threadIdx.x;
    const int n4 = N_NODES * D_FEAT / 4;
    float scale = 1.0f + eps[0];
    if (i < n4) {
        float4 v = ((const float4*)node_feat)[i];
        v.x *= scale; v.y *= scale; v.z *= scale; v.w *= scale;
        ((float4*)out)[i] = v;
    }
}

__global__ void fb_scatter(const float* __restrict__ node_feat,
                           const float* __restrict__ edge_feat,
                           const int* __restrict__ src,
                           const int* __restrict__ dst,
                           float* __restrict__ out) {
    int t = blockIdx.x * blockDim.x + threadIdx.x;
    int e = t >> 3;
    int g = t & 7;
    if (e >= N_EDGES) return;
    int s = src[e];
    int d = dst[e];
    float4 nf = ((const float4*)node_feat)[s * 8 + g];
    float4 ef = ((const float4*)edge_feat)[(size_t)e * 8 + g];
    float* op = out + (size_t)d * D_FEAT + g * 4;
    unsafeAtomicAdd(op + 0, fmaxf(nf.x + ef.x, 0.f));
    unsafeAtomicAdd(op + 1, fmaxf(nf.y + ef.y, 0.f));
    unsafeAtomicAdd(op + 2, fmaxf(nf.z + ef.z, 0.f));
    unsafeAtomicAdd(op + 3, fmaxf(nf.w + ef.w, 0.f));
}

extern "C" void kernel_launch(void* const* d_in, const int* in_sizes, int n_in,
                              void* d_out, int out_size, void* d_ws, size_t ws_size,
                              hipStream_t stream) {
    const float* node_feat = (const float*)d_in[0];
    const float* edge_feat = (const float*)d_in[1];
    const float* eps       = (const float*)d_in[2];
    const int*   src       = (const int*)d_in[3];
    const int*   dst       = (const int*)d_in[4];
    float* out = (float*)d_out;

    const int B = 256;
    const size_t need = ((size_t)WS_PAIR + 2ull * N_EDGES) * sizeof(int);

    if (ws_size < need) {
        // fallback: direct fp32 atomics (no ws)
        int n4 = N_NODES * D_FEAT / 4;
        fb_init_out<<<(n4 + B - 1) / B, B, 0, stream>>>(node_feat, eps, out);
        long long total = (long long)N_EDGES * 8;
        fb_scatter<<<(int)((total + B - 1) / B), B, 0, stream>>>(
            node_feat, edge_feat, src, dst, out);
        return;
    }

    int* ws = (int*)d_ws;
    int*  cnt   = ws + WS_CNT;
    int*  excl  = ws + WS_EXCL;
    int*  bsum  = ws + WS_BSUM;
    int*  bsumx = ws + WS_BSUMX;
    int*  rank  = ws + WS_RANK;
    int2* pair  = (int2*)(ws + WS_PAIR);

    hipMemsetAsync(cnt, 0, N_NODES * sizeof(int), stream);

    int nq = N_EDGES / 4;
    hist_rank<<<(nq + B - 1) / B, B, 0, stream>>>(dst, cnt, rank);
    scan_blocks<<<N_SCAN_BLOCKS, SCAN_BLOCK, 0, stream>>>(cnt, excl, bsum);
    scan_bsums<<<1, 64, 0, stream>>>(bsum, bsumx);

    scatter_pairs<<<(nq + B - 1) / B, B, 0, stream>>>(
        src, dst, excl, bsumx, rank, pair);

    long long ntotal = (long long)N_NODES * 8;
    reduce_gather<<<(int)((ntotal + B - 1) / B), B, 0, stream>>>(
        node_feat, edge_feat, eps, excl, bsumx, cnt, pair, out);
}